// Round 8
// baseline (477.368 us; speedup 1.0000x reference)
//
#include <hip/hip_runtime.h>
#include <cmath>

#ifndef M_PI
#define M_PI 3.14159265358979323846
#endif

typedef float v2f __attribute__((ext_vector_type(2)));
typedef float v4f __attribute__((ext_vector_type(4)));

constexpr int Dn = 200;
constexpr int DD = Dn * Dn;        // 40000
constexpr int NC = Dn * Dn * Dn;   // 8,000,000
constexpr int TPR = 25;            // threads per row (8 cells each)
constexpr int RPB = 10;            // rows per block (250 live threads)
constexpr int NBLK = (Dn * Dn) / RPB;  // 4000, divisible by 8 -> bijective XCD swizzle
constexpr float THR = 0.0100001f;  // conservative prefilter (exact test in slow path)

// scalar half extraction from v2f array at compile-time index
#define WH(W,k) (((k)&1) ? (W)[(k)>>1].y : (W)[(k)>>1].x)

// untied VOP3P packed f32 helpers: fresh "=v" outputs -> no forced copies
__device__ __forceinline__ v2f pk_add(v2f a, v2f b) {
    v2f d; asm("v_pk_add_f32 %0, %1, %2" : "=v"(d) : "v"(a), "v"(b)); return d;
}
__device__ __forceinline__ v2f pk_mul(v2f a, v2f b) {
    v2f d; asm("v_pk_mul_f32 %0, %1, %2" : "=v"(d) : "v"(a), "v"(b)); return d;
}
__device__ __forceinline__ v2f pk_fma(v2f a, v2f b, v2f c) {
    v2f d; asm("v_pk_fma_f32 %0, %1, %2, %3" : "=v"(d) : "v"(a), "v"(b), "v"(c)); return d;
}

__global__ __launch_bounds__(256, 2) void dem_step_kernel(
    const float* __restrict__ gx, const float* __restrict__ gy, const float* __restrict__ gz,
    const float* __restrict__ gvx, const float* __restrict__ gvy, const float* __restrict__ gvz,
    const float* __restrict__ gm, float* __restrict__ out,
    float ETAf, float dtOverPm, float gravTerm)
{
    const int t = threadIdx.x;
    if (t >= TPR * RPB) return;

    const int bid = blockIdx.x;
    const int sb = (bid & 7) * (NBLK / 8) + (bid >> 3);   // XCD-contiguous z-slabs

    const int rowid = sb * RPB + t / TPR;
    const int x0 = (t % TPR) * 8;
    const int zi = rowid / Dn;
    const int yj = rowid % Dn;
    const int cbase = rowid * Dn + x0;
    const int xl = (x0 == 0) ? (Dn - 2) : (x0 - 2);
    const int xr = (x0 == Dn - 8) ? 0 : (x0 + 8);

    // ---- center positions -> negated packs (x,y); z kept plain ----
    const v4f Xa = *reinterpret_cast<const v4f*>(gx + cbase);
    const v4f Xb = *reinterpret_cast<const v4f*>(gx + cbase + 4);
    const v4f Ya = *reinterpret_cast<const v4f*>(gy + cbase);
    const v4f Yb = *reinterpret_cast<const v4f*>(gy + cbase + 4);
    const v4f Za = *reinterpret_cast<const v4f*>(gz + cbase);
    const v4f Zb = *reinterpret_cast<const v4f*>(gz + cbase + 4);

    // even cell-pairs {0,1},{2,3},{4,5},{6,7}
    const v2f nXe[4] = {{-Xa.x,-Xa.y},{-Xa.z,-Xa.w},{-Xb.x,-Xb.y},{-Xb.z,-Xb.w}};
    const v2f nYe[4] = {{-Ya.x,-Ya.y},{-Ya.z,-Ya.w},{-Yb.x,-Yb.y},{-Yb.z,-Yb.w}};
    // odd cell-pairs {1,2},{3,4},{5,6} (built once per thread)
    const v2f nXo[3] = {{-Xa.y,-Xa.z},{-Xa.w,-Xb.x},{-Xb.y,-Xb.z}};
    const v2f nYo[3] = {{-Ya.y,-Ya.z},{-Ya.w,-Yb.x},{-Yb.y,-Yb.z}};

    // wrapped y row bases (compile-time indexed after unroll)
    int ybs[5];
    #pragma unroll
    for (int o = 0; o < 5; ++o) {
        int yy = yj + o - 2; yy += (yy < 0) ? Dn : 0; yy -= (yy >= Dn) ? Dn : 0;
        ybs[o] = yy * Dn;
    }

    float fxa[8] = {0,0,0,0,0,0,0,0};
    float fya[8] = {0,0,0,0,0,0,0,0};
    float fza[8] = {0,0,0,0,0,0,0,0};

    for (int i2 = 0; i2 < 5; ++i2) {
        int zz = zi + i2 - 2; zz += (zz < 0) ? Dn : 0; zz -= (zz >= Dn) ? Dn : 0;
        const int zbase = zz * DD;
        const bool zc = (i2 == 2);
        #pragma unroll
        for (int i3 = 0; i3 < 5; ++i3) {
            const int rowb = zbase + ybs[i3];

            // xy windows only: 6 naturally-aligned v2f per array (W[j] = floats {2j-2+x0...})
            v2f Wx[6], Wy[6];
            Wx[0] = *reinterpret_cast<const v2f*>(gx + rowb + xl);
            Wx[1] = *reinterpret_cast<const v2f*>(gx + rowb + x0);
            Wx[2] = *reinterpret_cast<const v2f*>(gx + rowb + x0 + 2);
            Wx[3] = *reinterpret_cast<const v2f*>(gx + rowb + x0 + 4);
            Wx[4] = *reinterpret_cast<const v2f*>(gx + rowb + x0 + 6);
            Wx[5] = *reinterpret_cast<const v2f*>(gx + rowb + xr);
            Wy[0] = *reinterpret_cast<const v2f*>(gy + rowb + xl);
            Wy[1] = *reinterpret_cast<const v2f*>(gy + rowb + x0);
            Wy[2] = *reinterpret_cast<const v2f*>(gy + rowb + x0 + 2);
            Wy[3] = *reinterpret_cast<const v2f*>(gy + rowb + x0 + 4);
            Wy[4] = *reinterpret_cast<const v2f*>(gy + rowb + x0 + 6);
            Wy[5] = *reinterpret_cast<const v2f*>(gy + rowb + xr);

            // ---- packed xy screen ----
            float mm0 = 1e30f, mm1 = 1e30f, mm2 = 1e30f, mm3 = 1e30f;
            #define PKMIN(dxv, dyv, u) { \
                const v2f _s = pk_fma((dyv),(dyv), pk_mul((dxv),(dxv))); \
                const int _m = (u) & 3; \
                if (_m == 0) { mm0 = fminf(_s.x, mm0); mm1 = fminf(_s.y, mm1); } \
                else if (_m == 1) { mm1 = fminf(_s.x, mm1); mm2 = fminf(_s.y, mm2); } \
                else if (_m == 2) { mm2 = fminf(_s.x, mm2); mm3 = fminf(_s.y, mm3); } \
                else { mm3 = fminf(_s.x, mm3); mm0 = fminf(_s.y, mm0); } }

            #pragma unroll
            for (int e = 0; e < 4; ++e) {          // even packs, o = 0 and 4
                PKMIN(pk_add(Wx[e],     nXe[e]), pk_add(Wy[e],     nYe[e]), e);
                PKMIN(pk_add(Wx[e + 2], nXe[e]), pk_add(Wy[e + 2], nYe[e]), e + 1);
            }
            const bool ctr = zc && (i3 == 2);
            if (!ctr) {                            // even packs, o = 2 (self column)
                #pragma unroll
                for (int e = 0; e < 4; ++e)
                    PKMIN(pk_add(Wx[e + 1], nXe[e]), pk_add(Wy[e + 1], nYe[e]), e + 2);
            }
            #pragma unroll
            for (int d = 0; d < 3; ++d) {          // odd packs, o = 1 and 3
                PKMIN(pk_add(Wx[d + 1], nXo[d]), pk_add(Wy[d + 1], nYo[d]), d);
                PKMIN(pk_add(Wx[d + 2], nXo[d]), pk_add(Wy[d + 2], nYo[d]), d + 2);
            }
            {   // scalar edge pairs: cell0 k=1,3 ; cell7 k=8,10
                float dx = WH(Wx,1) + nXe[0].x, dy = WH(Wy,1) + nYe[0].x;
                mm0 = fminf(fmaf(dy, dy, dx * dx), mm0);
                dx = WH(Wx,3) + nXe[0].x; dy = WH(Wy,3) + nYe[0].x;
                mm1 = fminf(fmaf(dy, dy, dx * dx), mm1);
                dx = WH(Wx,8) + nXe[3].y; dy = WH(Wy,8) + nYe[3].y;
                mm2 = fminf(fmaf(dy, dy, dx * dx), mm2);
                dx = WH(Wx,10) + nXe[3].y; dy = WH(Wy,10) + nYe[3].y;
                mm3 = fminf(fmaf(dy, dy, dx * dx), mm3);
            }
            #undef PKMIN

            // ---- rare slow path (~1.2% of rows): load z window, exact math ----
            if (fminf(fminf(mm0, mm1), fminf(mm2, mm3)) < THR) {
                v2f Wz[6];
                Wz[0] = *reinterpret_cast<const v2f*>(gz + rowb + xl);
                Wz[1] = *reinterpret_cast<const v2f*>(gz + rowb + x0);
                Wz[2] = *reinterpret_cast<const v2f*>(gz + rowb + x0 + 2);
                Wz[3] = *reinterpret_cast<const v2f*>(gz + rowb + x0 + 4);
                Wz[4] = *reinterpret_cast<const v2f*>(gz + rowb + x0 + 6);
                Wz[5] = *reinterpret_cast<const v2f*>(gz + rowb + xr);
                #pragma unroll
                for (int c = 0; c < 8; ++c) {
                    const float Xc = -((c & 1) ? nXe[c>>1].y : nXe[c>>1].x);
                    const float Yc = -((c & 1) ? nYe[c>>1].y : nYe[c>>1].x);
                    const float Zc = (c < 4) ? ((c==0)?Za.x:(c==1)?Za.y:(c==2)?Za.z:Za.w)
                                             : ((c==4)?Zb.x:(c==5)?Zb.y:(c==6)?Zb.z:Zb.w);
                    #pragma unroll
                    for (int o = 0; o < 5; ++o) {
                        const int k = c + o;
                        const float dx = Xc - WH(Wx, k);
                        const float dy = Yc - WH(Wy, k);
                        const float dz = Zc - WH(Wz, k);
                        const float sq = dx*dx + dy*dy + dz*dz;
                        if (sq < THR) {
                            const float dist = sqrtf(sq);
                            if (dist < 0.1f) {
                                const float d = fmaxf(dist, 1e-4f);
                                int nxi = x0 + c + o - 2;
                                nxi += (nxi < 0) ? Dn : 0;
                                nxi -= (nxi >= Dn) ? Dn : 0;
                                const int gi = rowb + nxi;
                                const float dvx = gvx[cbase + c] - gvx[gi];
                                const float dvy = gvy[cbase + c] - gvy[gi];
                                const float dvz = gvz[cbase + c] - gvz[gi];
                                const float vn = (dvx*dx + dvy*dy + dvz*dz) / d;
                                const float coef = 2.0f * (600000.0f*(dist - 0.1f) + ETAf*vn) / d;
                                fxa[c] += coef * dx;
                                fya[c] += coef * dy;
                                fza[c] += coef * dz;
                            }
                        }
                    }
                }
            }
        }
    }

    // ---- velocities + mask loaded only now ----
    const v4f VXa = *reinterpret_cast<const v4f*>(gvx + cbase);
    const v4f VXb = *reinterpret_cast<const v4f*>(gvx + cbase + 4);
    const v4f VYa = *reinterpret_cast<const v4f*>(gvy + cbase);
    const v4f VYb = *reinterpret_cast<const v4f*>(gvy + cbase + 4);
    const v4f VZa = *reinterpret_cast<const v4f*>(gvz + cbase);
    const v4f VZb = *reinterpret_cast<const v4f*>(gvz + cbase + 4);
    const v4f Ma  = *reinterpret_cast<const v4f*>(gm  + cbase);
    const v4f Mb  = *reinterpret_cast<const v4f*>(gm  + cbase + 4);

    #define C4(v,c) ((c)==0?(v).x:(c)==1?(v).y:(c)==2?(v).z:(v).w)
    float ox[8], oy[8], oz[8], ovx[8], ovy[8], ovz[8];
    #pragma unroll
    for (int c = 0; c < 8; ++c) {
        const float X = -((c & 1) ? nXe[c>>1].y : nXe[c>>1].x);
        const float Y = -((c & 1) ? nYe[c>>1].y : nYe[c>>1].x);
        const float Z = (c < 4) ? C4(Za, c) : C4(Zb, c - 4);
        const float VX = (c < 4) ? C4(VXa, c) : C4(VXb, c - 4);
        const float VY = (c < 4) ? C4(VYa, c) : C4(VYb, c - 4);
        const float VZ = (c < 4) ? C4(VZa, c) : C4(VZb, c - 4);
        const float M  = (c < 4) ? C4(Ma,  c) : C4(Mb,  c - 4);

        float fxb = 0.f, fyb = 0.f, fzb = 0.f;
        if (X > 0.1f && X < 0.15f) fxb = 600000.0f * (0.15f - X) - ETAf * VX;
        if (X > 9.9f)              fxb = -600000.0f * (((X - 10.0f) + 0.05f) + 0.05f) - ETAf * VX;
        if (Y > 0.1f && Y < 0.15f) fyb = 600000.0f * (0.15f - Y) - ETAf * VY;
        if (Y > 9.9f)              fyb = -600000.0f * (((Y - 10.0f) + 0.05f) + 0.05f) - ETAf * VY;
        if (Z > 0.1f && Z < 0.15f) fzb = 600000.0f * (0.15f - Z) - ETAf * VZ;
        if (Z > 9.9f)              fzb = -600000.0f * (((Z - 10.0f) + 0.05f) + 0.05f) - ETAf * VZ;

        const float am = dtOverPm * M;
        ovx[c] = VX + am * ((-fxa[c]) + fxb);
        ovy[c] = VY + am * ((-fya[c]) + fyb);
        ovz[c] = VZ + am * ((gravTerm - fza[c]) + fzb);
        ox[c] = X + 1e-4f * ovx[c];
        oy[c] = Y + 1e-4f * ovy[c];
        oz[c] = Z + 1e-4f * ovz[c];
    }
    #undef C4

    #define ST(arr, base) \
        __builtin_nontemporal_store((v4f){(arr)[0],(arr)[1],(arr)[2],(arr)[3]}, \
                                    reinterpret_cast<v4f*>(out + (base) + cbase)); \
        __builtin_nontemporal_store((v4f){(arr)[4],(arr)[5],(arr)[6],(arr)[7]}, \
                                    reinterpret_cast<v4f*>(out + (base) + cbase + 4));
    ST(ox,  0L * NC)
    ST(oy,  1L * NC)
    ST(oz,  2L * NC)
    ST(ovx, 3L * NC)
    ST(ovy, 4L * NC)
    ST(ovz, 5L * NC)
    #undef ST
}

extern "C" void kernel_launch(void* const* d_in, const int* in_sizes, int n_in,
                              void* d_out, int out_size, void* d_ws, size_t ws_size,
                              hipStream_t stream) {
    const float* gx  = (const float*)d_in[0];
    const float* gy  = (const float*)d_in[1];
    const float* gz  = (const float*)d_in[2];
    const float* gvx = (const float*)d_in[3];
    const float* gvy = (const float*)d_in[4];
    const float* gvz = (const float*)d_in[5];
    const float* gm  = (const float*)d_in[6];
    float* out = (float*)d_out;

    const double KN  = 600000.0;
    const double PM  = 4.0 / 3.0 * 3.1415 * std::pow(0.05, 3) * 2700.0;
    const double alpha = -std::log(0.5) / M_PI;
    const double gamma = alpha / std::sqrt(alpha * alpha + 1.0);
    const double ETA = 2.0 * gamma * std::sqrt(KN * PM);

    const float ETAf     = (float)ETA;
    const float dtOverPm = (float)(0.0001 / PM);
    const float gravTerm = (float)(-9.8 * PM);

    dem_step_kernel<<<NBLK, 256, 0, stream>>>(gx, gy, gz, gvx, gvy, gvz, gm, out,
                                              ETAf, dtOverPm, gravTerm);
}